// Round 1
// baseline (1491.270 us; speedup 1.0000x reference)
//
#include <hip/hip_runtime.h>

// ---------------- problem constants ----------------
#define NNODES 100000
#define NEDGES 1600000
#define KDIM 256          // IN
#define CDIM 256          // H*F
#define NHEAD 4
#define FDIM 64
#define NEG 0.05f

// ---------------- GEMM tile params ----------------
#define MT 32             // rows per block
#define KC 16             // k-chunk

// Fused dual GEMM: feat_src = feat @ W_fc^T  (to ws)
//                  rst0     = feat @ W_res^T + bias (to d_out)
// Epilogue: el[n,h] = dot(feat_src[n,h,:], attn_l[h,:]), er likewise.
// Thread c = tid owns output column c for MT rows. Wave w == head w.
__global__ __launch_bounds__(256) void gemm_dual(
    const float* __restrict__ feat, const float* __restrict__ Wfc,
    const float* __restrict__ Wres, const float* __restrict__ bias,
    const float* __restrict__ attn_l, const float* __restrict__ attn_r,
    float* __restrict__ feat_src, float* __restrict__ rst,
    float* __restrict__ el, float* __restrict__ er)
{
    __shared__ float sfeat[MT][KC];
    const int tid = threadIdx.x;
    const int row0 = blockIdx.x * MT;
    const int c = tid;

    float acc1[MT], acc2[MT];
#pragma unroll
    for (int r = 0; r < MT; ++r) { acc1[r] = 0.f; acc2[r] = 0.f; }

    const float* wf = Wfc + (size_t)c * KDIM;
    const float* wr = Wres + (size_t)c * KDIM;

    for (int k0 = 0; k0 < KDIM; k0 += KC) {
        __syncthreads();
#pragma unroll
        for (int i = 0; i < (MT * KC) / 256; ++i) {
            int flat = tid + i * 256;
            int r = flat / KC, kk = flat % KC;
            sfeat[r][kk] = feat[(size_t)(row0 + r) * KDIM + k0 + kk];
        }
        __syncthreads();

        float4 w1[KC / 4], w2[KC / 4];
#pragma unroll
        for (int j = 0; j < KC / 4; ++j) {
            w1[j] = *(const float4*)(wf + k0 + j * 4);
            w2[j] = *(const float4*)(wr + k0 + j * 4);
        }
#pragma unroll
        for (int r = 0; r < MT; ++r) {
#pragma unroll
            for (int j = 0; j < KC / 4; ++j) {
                float4 f = *(const float4*)(&sfeat[r][j * 4]);
                acc1[r] = fmaf(f.x, w1[j].x, acc1[r]);
                acc1[r] = fmaf(f.y, w1[j].y, acc1[r]);
                acc1[r] = fmaf(f.z, w1[j].z, acc1[r]);
                acc1[r] = fmaf(f.w, w1[j].w, acc1[r]);
                acc2[r] = fmaf(f.x, w2[j].x, acc2[r]);
                acc2[r] = fmaf(f.y, w2[j].y, acc2[r]);
                acc2[r] = fmaf(f.z, w2[j].z, acc2[r]);
                acc2[r] = fmaf(f.w, w2[j].w, acc2[r]);
            }
        }
    }

    const float b = bias[c];
#pragma unroll
    for (int r = 0; r < MT; ++r) {
        size_t idx = (size_t)(row0 + r) * CDIM + c;
        feat_src[idx] = acc1[r];
        rst[idx] = acc2[r] + b;
    }

    // Epilogue: el/er via wave-64 reduction (wave h handles head h)
    const int h = tid >> 6, lane = tid & 63;
    const float al = attn_l[h * FDIM + lane];
    const float ar = attn_r[h * FDIM + lane];
#pragma unroll
    for (int r = 0; r < MT; ++r) {
        float pl = acc1[r] * al;
        float pr = acc1[r] * ar;
#pragma unroll
        for (int d = 32; d > 0; d >>= 1) {
            pl += __shfl_down(pl, d);
            pr += __shfl_down(pr, d);
        }
        if (lane == 0) {
            el[(size_t)(row0 + r) * NHEAD + h] = pl;
            er[(size_t)(row0 + r) * NHEAD + h] = pr;
        }
    }
}

// ---------------- CSR build (order-free grouping by dst) ----------------
__global__ __launch_bounds__(256) void count_kernel(const int* __restrict__ dst,
                                                    int* __restrict__ cnt)
{
    int e = blockIdx.x * 256 + threadIdx.x;
    if (e < NEDGES) atomicAdd(&cnt[dst[e]], 1);
}

__global__ __launch_bounds__(256) void offset_kernel(const int* __restrict__ cnt,
                                                     int* __restrict__ off,
                                                     int* __restrict__ cursor,
                                                     int* __restrict__ total)
{
    int n = blockIdx.x * 256 + threadIdx.x;
    if (n < NNODES) {
        int c = cnt[n];
        int o = atomicAdd(total, c);   // arbitrary but disjoint ranges — grouping only
        off[n] = o;
        cursor[n] = o;
    }
}

__global__ __launch_bounds__(256) void scatter_kernel(const int* __restrict__ dst,
                                                      int* __restrict__ cursor,
                                                      int* __restrict__ perm)
{
    int e = blockIdx.x * 256 + threadIdx.x;
    if (e < NEDGES) {
        int p = atomicAdd(&cursor[dst[e]], 1);
        perm[p] = e;
    }
}

// ---------------- per-dst softmax + SpMM aggregation ----------------
// One block (256 threads) per dst node. Thread tid owns feature column tid;
// head of a thread = tid>>6 (== its wave).
__global__ __launch_bounds__(256) void agg_kernel(
    const int* __restrict__ src, const int* __restrict__ perm,
    const int* __restrict__ off, const int* __restrict__ cnt,
    const float* __restrict__ el, const float* __restrict__ er,
    const float* __restrict__ feat_src,
    float* __restrict__ rst, float* __restrict__ a_out)
{
    const int n = blockIdx.x;
    const int deg = cnt[n];
    if (deg == 0) return;              // block-uniform; rst keeps residual
    const int o0 = off[n];
    const int tid = threadIdx.x;
    const int wv = tid >> 6, lane = tid & 63;

    const float4 er4 = *(const float4*)(er + (size_t)n * NHEAD);

    __shared__ float red[4][4];                    // [wave][head]
    __shared__ __align__(16) float a_sh[64][4];
    __shared__ int s_sh[64];

    // ---- pass 1: per-head max of leaky_relu(el[src]+er[n]) ----
    float m0 = -1e30f, m1 = -1e30f, m2 = -1e30f, m3 = -1e30f;
    for (int i = tid; i < deg; i += 256) {
        int e = perm[o0 + i];
        int s = src[e];
        float4 el4 = *(const float4*)(el + (size_t)s * NHEAD);
        float l0 = el4.x + er4.x; l0 = l0 > 0.f ? l0 : NEG * l0;
        float l1 = el4.y + er4.y; l1 = l1 > 0.f ? l1 : NEG * l1;
        float l2 = el4.z + er4.z; l2 = l2 > 0.f ? l2 : NEG * l2;
        float l3 = el4.w + er4.w; l3 = l3 > 0.f ? l3 : NEG * l3;
        m0 = fmaxf(m0, l0); m1 = fmaxf(m1, l1);
        m2 = fmaxf(m2, l2); m3 = fmaxf(m3, l3);
    }
#pragma unroll
    for (int d = 32; d > 0; d >>= 1) {
        m0 = fmaxf(m0, __shfl_down(m0, d));
        m1 = fmaxf(m1, __shfl_down(m1, d));
        m2 = fmaxf(m2, __shfl_down(m2, d));
        m3 = fmaxf(m3, __shfl_down(m3, d));
    }
    if (lane == 0) { red[wv][0] = m0; red[wv][1] = m1; red[wv][2] = m2; red[wv][3] = m3; }
    __syncthreads();
    m0 = fmaxf(fmaxf(red[0][0], red[1][0]), fmaxf(red[2][0], red[3][0]));
    m1 = fmaxf(fmaxf(red[0][1], red[1][1]), fmaxf(red[2][1], red[3][1]));
    m2 = fmaxf(fmaxf(red[0][2], red[1][2]), fmaxf(red[2][2], red[3][2]));
    m3 = fmaxf(fmaxf(red[0][3], red[1][3]), fmaxf(red[2][3], red[3][3]));
    __syncthreads();

    // ---- pass 2: per-head sum of exp ----
    float s0 = 0.f, s1 = 0.f, s2 = 0.f, s3 = 0.f;
    for (int i = tid; i < deg; i += 256) {
        int e = perm[o0 + i];
        int s = src[e];
        float4 el4 = *(const float4*)(el + (size_t)s * NHEAD);
        float l0 = el4.x + er4.x; l0 = l0 > 0.f ? l0 : NEG * l0;
        float l1 = el4.y + er4.y; l1 = l1 > 0.f ? l1 : NEG * l1;
        float l2 = el4.z + er4.z; l2 = l2 > 0.f ? l2 : NEG * l2;
        float l3 = el4.w + er4.w; l3 = l3 > 0.f ? l3 : NEG * l3;
        s0 += __expf(l0 - m0); s1 += __expf(l1 - m1);
        s2 += __expf(l2 - m2); s3 += __expf(l3 - m3);
    }
#pragma unroll
    for (int d = 32; d > 0; d >>= 1) {
        s0 += __shfl_down(s0, d); s1 += __shfl_down(s1, d);
        s2 += __shfl_down(s2, d); s3 += __shfl_down(s3, d);
    }
    if (lane == 0) { red[wv][0] = s0; red[wv][1] = s1; red[wv][2] = s2; red[wv][3] = s3; }
    __syncthreads();
    s0 = red[0][0] + red[1][0] + red[2][0] + red[3][0];
    s1 = red[0][1] + red[1][1] + red[2][1] + red[3][1];
    s2 = red[0][2] + red[1][2] + red[2][2] + red[3][2];
    s3 = red[0][3] + red[1][3] + red[2][3] + red[3][3];
    const float i0 = 1.f / fmaxf(s0, 1e-20f);
    const float i1 = 1.f / fmaxf(s1, 1e-20f);
    const float i2 = 1.f / fmaxf(s2, 1e-20f);
    const float i3 = 1.f / fmaxf(s3, 1e-20f);

    // ---- pass 3: chunked a-computation + feature accumulation ----
    float acc = 0.f;
    const int h = wv;
    for (int base = 0; base < deg; base += 64) {
        int nc = min(64, deg - base);
        __syncthreads();   // protect a_sh/s_sh from previous chunk's readers
        if (tid < nc) {
            int e = perm[o0 + base + tid];
            int s = src[e];
            float4 el4 = *(const float4*)(el + (size_t)s * NHEAD);
            float l0 = el4.x + er4.x; l0 = l0 > 0.f ? l0 : NEG * l0;
            float l1 = el4.y + er4.y; l1 = l1 > 0.f ? l1 : NEG * l1;
            float l2 = el4.z + er4.z; l2 = l2 > 0.f ? l2 : NEG * l2;
            float l3 = el4.w + er4.w; l3 = l3 > 0.f ? l3 : NEG * l3;
            float a0 = __expf(l0 - m0) * i0;
            float a1 = __expf(l1 - m1) * i1;
            float a2 = __expf(l2 - m2) * i2;
            float a3 = __expf(l3 - m3) * i3;
            *(float4*)(&a_sh[tid][0]) = make_float4(a0, a1, a2, a3);
            s_sh[tid] = s;
            *(float4*)(a_out + (size_t)e * NHEAD) = make_float4(a0, a1, a2, a3);
        }
        __syncthreads();
        for (int i = 0; i < nc; ++i) {
            float v = feat_src[(size_t)s_sh[i] * CDIM + tid];   // coalesced 1KB/edge
            acc = fmaf(a_sh[i][h], v, acc);
        }
    }
    rst[(size_t)n * CDIM + tid] += acc;   // add on top of residual written by GEMM
}

// ---------------- launch ----------------
extern "C" void kernel_launch(void* const* d_in, const int* in_sizes, int n_in,
                              void* d_out, int out_size, void* d_ws, size_t ws_size,
                              hipStream_t stream) {
    const float* feat   = (const float*)d_in[0];
    const int*   src    = (const int*)d_in[1];
    const int*   dst    = (const int*)d_in[2];
    const float* Wfc    = (const float*)d_in[3];
    const float* attn_l = (const float*)d_in[4];
    const float* attn_r = (const float*)d_in[5];
    const float* Wres   = (const float*)d_in[6];
    const float* bias   = (const float*)d_in[7];

    float* rst   = (float*)d_out;                                  // N*H*F
    float* a_out = (float*)d_out + (size_t)NNODES * CDIM;          // E*H

    // workspace layout
    float* feat_src = (float*)d_ws;                                // N*256
    float* el  = feat_src + (size_t)NNODES * CDIM;                 // N*4
    float* er  = el + (size_t)NNODES * NHEAD;                      // N*4
    int* cnt    = (int*)(er + (size_t)NNODES * NHEAD);             // N
    int* off    = cnt + NNODES;                                    // N
    int* cursor = off + NNODES;                                    // N
    int* total  = cursor + NNODES;                                 // 4 (pad)
    int* perm   = total + 4;                                       // E

    hipMemsetAsync(cnt, 0, NNODES * sizeof(int), stream);
    hipMemsetAsync(total, 0, 4 * sizeof(int), stream);

    gemm_dual<<<NNODES / MT, 256, 0, stream>>>(feat, Wfc, Wres, bias, attn_l, attn_r,
                                               feat_src, rst, el, er);
    count_kernel<<<(NEDGES + 255) / 256, 256, 0, stream>>>(dst, cnt);
    offset_kernel<<<(NNODES + 255) / 256, 256, 0, stream>>>(cnt, off, cursor, total);
    scatter_kernel<<<(NEDGES + 255) / 256, 256, 0, stream>>>(dst, cursor, perm);
    agg_kernel<<<NNODES, 256, 0, stream>>>(src, perm, off, cnt, el, er,
                                           feat_src, rst, a_out);
}

// Round 2
// 916.669 us; speedup vs baseline: 1.6268x; 1.6268x over previous
//
#include <hip/hip_runtime.h>

// ---------------- problem constants ----------------
#define NNODES 100000
#define NEDGES 1600000
#define KDIM 256          // IN
#define CDIM 256          // H*F
#define NHEAD 4
#define FDIM 64
#define NEG 0.05f

typedef short bf16x8 __attribute__((ext_vector_type(8)));   // 8 bf16 in 4 VGPRs
typedef float f32x4  __attribute__((ext_vector_type(4)));
typedef __attribute__((address_space(3))) void*       lds_vp;
typedef __attribute__((address_space(1))) const void* glb_cvp;

__device__ __forceinline__ unsigned short f2b(float x) {   // fp32 -> bf16 RNE
    unsigned int u = __float_as_uint(x);
    return (unsigned short)((u + 0x7FFFu + ((u >> 16) & 1u)) >> 16);
}
__device__ __forceinline__ float b2f(unsigned short b) {
    return __uint_as_float(((unsigned int)b) << 16);
}

// ---------------- fp32 -> bf16 converts ----------------
__global__ __launch_bounds__(256) void cvt_feat(const float* __restrict__ in,
                                                unsigned short* __restrict__ out)
{
    int i = (blockIdx.x * 256 + threadIdx.x) * 4;   // exact: 25.6M/4/256 = 25000 blocks
    float4 v = *(const float4*)(in + i);
    ushort4 o;
    o.x = f2b(v.x); o.y = f2b(v.y); o.z = f2b(v.z); o.w = f2b(v.w);
    *(ushort4*)(out + i) = o;
}

// Wb = concat(Wfc, Wres) as [512][256] bf16
__global__ __launch_bounds__(256) void cvt_w(const float* __restrict__ Wfc,
                                             const float* __restrict__ Wres,
                                             unsigned short* __restrict__ out)
{
    int i = (blockIdx.x * 256 + threadIdx.x) * 4;   // 131072/4/256 = 128 blocks
    float4 v = (i < 65536) ? *(const float4*)(Wfc + i)
                           : *(const float4*)(Wres + (i - 65536));
    ushort4 o;
    o.x = f2b(v.x); o.y = f2b(v.y); o.z = f2b(v.z); o.w = f2b(v.w);
    *(ushort4*)(out + i) = o;
}

// ---------------- bf16 MFMA dual GEMM ----------------
// C[m, 0:256]  -> fsb (bf16)  = feat @ Wfc^T
// C[m, 256:512]-> rst (fp32)  = feat @ Wres^T + bias
// Block: 256 thr (4 waves, 2x2), tile 128x128, BK=64, K=256.
// LDS chunk swizzle: 16B chunk kc of row r stored at slot kc^(r&7) so that
// global_load_lds staging stays lane-contiguous AND ds_read_b128 fragment
// reads spread evenly over banks.
__global__ __launch_bounds__(256) void gemm_mfma(
    const unsigned short* __restrict__ featb,   // [N][256] bf16
    const unsigned short* __restrict__ Wb,      // [512][256] bf16
    const float* __restrict__ bias,
    unsigned short* __restrict__ fsb,           // [N][256] bf16
    float* __restrict__ rst)                    // [N][256] fp32
{
    __shared__ __align__(16) char smem[32768];
    char* sA = smem;            // 128 rows x 64 bf16 = 16KB
    char* sB = smem + 16384;

    const int tid = threadIdx.x;
    const int w = tid >> 6, l = tid & 63;
    const int wm = w & 1, wn = w >> 1;
    const int row0 = blockIdx.x * 128;
    const int ny = blockIdx.y;          // 0..3 -> virtual cols [ny*128, ny*128+128)

    f32x4 acc[4][4];
#pragma unroll
    for (int tm = 0; tm < 4; ++tm)
#pragma unroll
        for (int tn = 0; tn < 4; ++tn) acc[tm][tn] = (f32x4)0.f;

    const int srow = tid >> 3;          // staging row (+32 per iter)
    const int sslot = tid & 7;          // staging 16B slot within row

    for (int k0 = 0; k0 < 256; k0 += 64) {
        if (k0) __syncthreads();        // protect LDS from overwrite
        // ---- stage A (feat rows) ----
#pragma unroll
        for (int it = 0; it < 4; ++it) {
            int r = srow + it * 32;
            int gr = row0 + r; if (gr >= NNODES) gr = NNODES - 1;   // tail clamp
            int kc = sslot ^ (r & 7);
            const unsigned short* g = featb + (size_t)gr * 256 + k0 + kc * 8;
            void* sp = sA + (it * 256 + w * 64) * 16;   // wave-uniform base
            __builtin_amdgcn_global_load_lds((glb_cvp)g, (lds_vp)sp, 16, 0, 0);
        }
        // ---- stage B (W rows) ----
#pragma unroll
        for (int it = 0; it < 4; ++it) {
            int r = srow + it * 32;
            int kc = sslot ^ (r & 7);
            const unsigned short* g = Wb + (size_t)(ny * 128 + r) * 256 + k0 + kc * 8;
            void* sp = sB + (it * 256 + w * 64) * 16;
            __builtin_amdgcn_global_load_lds((glb_cvp)g, (lds_vp)sp, 16, 0, 0);
        }
        __syncthreads();

        const int quad = l >> 4;
#pragma unroll
        for (int kk = 0; kk < 2; ++kk) {
            const int kc = kk * 4 + quad;           // 16B chunk index along K
            bf16x8 af[4], bq[4];
#pragma unroll
            for (int tm = 0; tm < 4; ++tm) {
                int m = wm * 64 + tm * 16 + (l & 15);
                af[tm] = *(const bf16x8*)(sA + m * 128 + ((kc ^ (m & 7)) * 16));
            }
#pragma unroll
            for (int tn = 0; tn < 4; ++tn) {
                int n = wn * 64 + tn * 16 + (l & 15);
                bq[tn] = *(const bf16x8*)(sB + n * 128 + ((kc ^ (n & 7)) * 16));
            }
#pragma unroll
            for (int tm = 0; tm < 4; ++tm)
#pragma unroll
                for (int tn = 0; tn < 4; ++tn)
                    acc[tm][tn] = __builtin_amdgcn_mfma_f32_16x16x32_bf16(
                        af[tm], bq[tn], acc[tm][tn], 0, 0, 0);
        }
    }

    // ---- epilogue: C layout col=lane&15, row=(lane>>4)*4+reg ----
    const int quad = l >> 4, c15 = l & 15;
    if (ny < 2) {   // feat_src -> bf16
#pragma unroll
        for (int tm = 0; tm < 4; ++tm) {
            int rb = row0 + wm * 64 + tm * 16 + quad * 4;
#pragma unroll
            for (int tn = 0; tn < 4; ++tn) {
                int cg = ny * 128 + wn * 64 + tn * 16 + c15;
#pragma unroll
                for (int reg = 0; reg < 4; ++reg) {
                    int r = rb + reg;
                    if (r < NNODES) fsb[(size_t)r * 256 + cg] = f2b(acc[tm][tn][reg]);
                }
            }
        }
    } else {        // residual + bias -> rst fp32
#pragma unroll
        for (int tm = 0; tm < 4; ++tm) {
            int rb = row0 + wm * 64 + tm * 16 + quad * 4;
#pragma unroll
            for (int tn = 0; tn < 4; ++tn) {
                int co = (ny - 2) * 128 + wn * 64 + tn * 16 + c15;
                float b = bias[co];
#pragma unroll
                for (int reg = 0; reg < 4; ++reg) {
                    int r = rb + reg;
                    if (r < NNODES) rst[(size_t)r * 256 + co] = acc[tm][tn][reg] + b;
                }
            }
        }
    }
}

// ---------------- el/er: per-node attention logits ----------------
__global__ __launch_bounds__(256) void eler_kernel(
    const unsigned short* __restrict__ fsb,
    const float* __restrict__ attn_l, const float* __restrict__ attn_r,
    float* __restrict__ el, float* __restrict__ er)
{
    const int n = blockIdx.x, tid = threadIdx.x;
    const int h = tid >> 6, lane = tid & 63;
    float v = b2f(fsb[(size_t)n * 256 + tid]);
    float pl = v * attn_l[tid];     // attn_l flat [H*F] == [256]
    float pr = v * attn_r[tid];
#pragma unroll
    for (int d = 32; d > 0; d >>= 1) {
        pl += __shfl_down(pl, d);
        pr += __shfl_down(pr, d);
    }
    if (lane == 0) { el[n * NHEAD + h] = pl; er[n * NHEAD + h] = pr; }
}

// ---------------- CSR build (order-free grouping by dst) ----------------
__global__ __launch_bounds__(256) void count_kernel(const int* __restrict__ dst,
                                                    int* __restrict__ cnt)
{
    int e = blockIdx.x * 256 + threadIdx.x;
    if (e < NEDGES) atomicAdd(&cnt[dst[e]], 1);
}

__global__ __launch_bounds__(256) void offset_kernel(const int* __restrict__ cnt,
                                                     int* __restrict__ off,
                                                     int* __restrict__ cursor,
                                                     int* __restrict__ total)
{
    int n = blockIdx.x * 256 + threadIdx.x;
    if (n < NNODES) {
        int c = cnt[n];
        int o = atomicAdd(total, c);   // arbitrary but disjoint ranges
        off[n] = o;
        cursor[n] = o;
    }
}

__global__ __launch_bounds__(256) void scatter_kernel(const int* __restrict__ dst,
                                                      int* __restrict__ cursor,
                                                      int* __restrict__ perm)
{
    int e = blockIdx.x * 256 + threadIdx.x;
    if (e < NEDGES) {
        int p = atomicAdd(&cursor[dst[e]], 1);
        perm[p] = e;
    }
}

// ---------------- per-dst softmax + SpMM aggregation ----------------
__global__ __launch_bounds__(256) void agg_kernel(
    const int* __restrict__ src, const int* __restrict__ perm,
    const int* __restrict__ off, const int* __restrict__ cnt,
    const float* __restrict__ el, const float* __restrict__ er,
    const unsigned short* __restrict__ fsb,
    float* __restrict__ rst, float* __restrict__ a_out)
{
    const int n = blockIdx.x;
    const int deg = cnt[n];
    if (deg == 0) return;              // rst keeps residual
    const int o0 = off[n];
    const int tid = threadIdx.x;
    const int wv = tid >> 6, lane = tid & 63;

    const float4 er4 = *(const float4*)(er + (size_t)n * NHEAD);

    __shared__ float red[4][4];
    __shared__ __align__(16) float a_sh[64][4];
    __shared__ int s_sh[64];

    // ---- pass 1: per-head max ----
    float m0 = -1e30f, m1 = -1e30f, m2 = -1e30f, m3 = -1e30f;
    for (int i = tid; i < deg; i += 256) {
        int e = perm[o0 + i];
        int s = src[e];
        float4 el4 = *(const float4*)(el + (size_t)s * NHEAD);
        float l0 = el4.x + er4.x; l0 = l0 > 0.f ? l0 : NEG * l0;
        float l1 = el4.y + er4.y; l1 = l1 > 0.f ? l1 : NEG * l1;
        float l2 = el4.z + er4.z; l2 = l2 > 0.f ? l2 : NEG * l2;
        float l3 = el4.w + er4.w; l3 = l3 > 0.f ? l3 : NEG * l3;
        m0 = fmaxf(m0, l0); m1 = fmaxf(m1, l1);
        m2 = fmaxf(m2, l2); m3 = fmaxf(m3, l3);
    }
#pragma unroll
    for (int d = 32; d > 0; d >>= 1) {
        m0 = fmaxf(m0, __shfl_down(m0, d));
        m1 = fmaxf(m1, __shfl_down(m1, d));
        m2 = fmaxf(m2, __shfl_down(m2, d));
        m3 = fmaxf(m3, __shfl_down(m3, d));
    }
    if (lane == 0) { red[wv][0] = m0; red[wv][1] = m1; red[wv][2] = m2; red[wv][3] = m3; }
    __syncthreads();
    m0 = fmaxf(fmaxf(red[0][0], red[1][0]), fmaxf(red[2][0], red[3][0]));
    m1 = fmaxf(fmaxf(red[0][1], red[1][1]), fmaxf(red[2][1], red[3][1]));
    m2 = fmaxf(fmaxf(red[0][2], red[1][2]), fmaxf(red[2][2], red[3][2]));
    m3 = fmaxf(fmaxf(red[0][3], red[1][3]), fmaxf(red[2][3], red[3][3]));
    __syncthreads();

    // ---- pass 2: per-head sum of exp ----
    float s0 = 0.f, s1 = 0.f, s2 = 0.f, s3 = 0.f;
    for (int i = tid; i < deg; i += 256) {
        int e = perm[o0 + i];
        int s = src[e];
        float4 el4 = *(const float4*)(el + (size_t)s * NHEAD);
        float l0 = el4.x + er4.x; l0 = l0 > 0.f ? l0 : NEG * l0;
        float l1 = el4.y + er4.y; l1 = l1 > 0.f ? l1 : NEG * l1;
        float l2 = el4.z + er4.z; l2 = l2 > 0.f ? l2 : NEG * l2;
        float l3 = el4.w + er4.w; l3 = l3 > 0.f ? l3 : NEG * l3;
        s0 += __expf(l0 - m0); s1 += __expf(l1 - m1);
        s2 += __expf(l2 - m2); s3 += __expf(l3 - m3);
    }
#pragma unroll
    for (int d = 32; d > 0; d >>= 1) {
        s0 += __shfl_down(s0, d); s1 += __shfl_down(s1, d);
        s2 += __shfl_down(s2, d); s3 += __shfl_down(s3, d);
    }
    if (lane == 0) { red[wv][0] = s0; red[wv][1] = s1; red[wv][2] = s2; red[wv][3] = s3; }
    __syncthreads();
    s0 = red[0][0] + red[1][0] + red[2][0] + red[3][0];
    s1 = red[0][1] + red[1][1] + red[2][1] + red[3][1];
    s2 = red[0][2] + red[1][2] + red[2][2] + red[3][2];
    s3 = red[0][3] + red[1][3] + red[2][3] + red[3][3];
    const float i0 = 1.f / fmaxf(s0, 1e-20f);
    const float i1 = 1.f / fmaxf(s1, 1e-20f);
    const float i2 = 1.f / fmaxf(s2, 1e-20f);
    const float i3 = 1.f / fmaxf(s3, 1e-20f);

    // ---- pass 3: a + bf16 feature gather/accumulate ----
    float acc = 0.f;
    const int h = wv;
    for (int base = 0; base < deg; base += 64) {
        int nc = min(64, deg - base);
        __syncthreads();
        if (tid < nc) {
            int e = perm[o0 + base + tid];
            int s = src[e];
            float4 el4 = *(const float4*)(el + (size_t)s * NHEAD);
            float l0 = el4.x + er4.x; l0 = l0 > 0.f ? l0 : NEG * l0;
            float l1 = el4.y + er4.y; l1 = l1 > 0.f ? l1 : NEG * l1;
            float l2 = el4.z + er4.z; l2 = l2 > 0.f ? l2 : NEG * l2;
            float l3 = el4.w + er4.w; l3 = l3 > 0.f ? l3 : NEG * l3;
            float a0 = __expf(l0 - m0) * i0;
            float a1 = __expf(l1 - m1) * i1;
            float a2 = __expf(l2 - m2) * i2;
            float a3 = __expf(l3 - m3) * i3;
            *(float4*)(&a_sh[tid][0]) = make_float4(a0, a1, a2, a3);
            s_sh[tid] = s;
            *(float4*)(a_out + (size_t)e * NHEAD) = make_float4(a0, a1, a2, a3);
        }
        __syncthreads();
        for (int i = 0; i < nc; ++i) {
            float v = b2f(fsb[(size_t)s_sh[i] * CDIM + tid]);
            acc = fmaf(a_sh[i][h], v, acc);
        }
    }
    rst[(size_t)n * CDIM + tid] += acc;
}

// ---------------- launch ----------------
extern "C" void kernel_launch(void* const* d_in, const int* in_sizes, int n_in,
                              void* d_out, int out_size, void* d_ws, size_t ws_size,
                              hipStream_t stream) {
    const float* feat   = (const float*)d_in[0];
    const int*   src    = (const int*)d_in[1];
    const int*   dst    = (const int*)d_in[2];
    const float* Wfc    = (const float*)d_in[3];
    const float* attn_l = (const float*)d_in[4];
    const float* attn_r = (const float*)d_in[5];
    const float* Wres   = (const float*)d_in[6];
    const float* bias   = (const float*)d_in[7];

    float* rst   = (float*)d_out;                              // N*256
    float* a_out = (float*)d_out + (size_t)NNODES * CDIM;      // E*4

    // workspace layout (~113 MB)
    unsigned short* featb = (unsigned short*)d_ws;             // N*256 bf16
    unsigned short* fsb   = featb + (size_t)NNODES * CDIM;     // N*256 bf16
    unsigned short* Wb    = fsb + (size_t)NNODES * CDIM;       // 512*256 bf16
    float* el  = (float*)(Wb + 512 * 256);                     // N*4
    float* er  = el + (size_t)NNODES * NHEAD;                  // N*4
    int* cnt    = (int*)(er + (size_t)NNODES * NHEAD);         // N
    int* off    = cnt + NNODES;                                // N
    int* cursor = off + NNODES;                                // N
    int* total  = cursor + NNODES;                             // 4
    int* perm   = total + 4;                                   // E

    hipMemsetAsync(cnt, 0, NNODES * sizeof(int), stream);
    hipMemsetAsync(total, 0, 4 * sizeof(int), stream);

    cvt_feat<<<(NNODES * CDIM) / (256 * 4), 256, 0, stream>>>(feat, featb);
    cvt_w<<<(512 * 256) / (256 * 4), 256, 0, stream>>>(Wfc, Wres, Wb);

    dim3 ggrid((NNODES + 127) / 128, 4);
    gemm_mfma<<<ggrid, 256, 0, stream>>>(featb, Wb, bias, fsb, rst);

    eler_kernel<<<NNODES, 256, 0, stream>>>(fsb, attn_l, attn_r, el, er);

    count_kernel<<<(NEDGES + 255) / 256, 256, 0, stream>>>(dst, cnt);
    offset_kernel<<<(NNODES + 255) / 256, 256, 0, stream>>>(cnt, off, cursor, total);
    scatter_kernel<<<(NEDGES + 255) / 256, 256, 0, stream>>>(dst, cursor, perm);
    agg_kernel<<<NNODES, 256, 0, stream>>>(src, perm, off, cnt, el, er,
                                           fsb, rst, a_out);
}

// Round 3
// 741.426 us; speedup vs baseline: 2.0114x; 1.2364x over previous
//
#include <hip/hip_runtime.h>

// ---------------- problem constants ----------------
#define NNODES 100000
#define NEDGES 1600000
#define KDIM 256          // IN
#define CDIM 256          // H*F
#define NHEAD 4
#define FDIM 64
#define NEG 0.05f

typedef short bf16x8 __attribute__((ext_vector_type(8)));   // 8 bf16 in 4 VGPRs
typedef float f32x4  __attribute__((ext_vector_type(4)));
typedef __attribute__((address_space(3))) void*       lds_vp;
typedef __attribute__((address_space(1))) const void* glb_cvp;

__device__ __forceinline__ unsigned short f2b(float x) {   // fp32 -> bf16 RNE
    unsigned int u = __float_as_uint(x);
    return (unsigned short)((u + 0x7FFFu + ((u >> 16) & 1u)) >> 16);
}
__device__ __forceinline__ float b2f(unsigned short b) {
    return __uint_as_float(((unsigned int)b) << 16);
}
__device__ __forceinline__ float lrelu(float x) { return x > 0.f ? x : NEG * x; }

// ---------------- fp32 -> bf16 converts ----------------
__global__ __launch_bounds__(256) void cvt_feat(const float* __restrict__ in,
                                                unsigned short* __restrict__ out)
{
    int i = (blockIdx.x * 256 + threadIdx.x) * 4;
    float4 v = *(const float4*)(in + i);
    ushort4 o;
    o.x = f2b(v.x); o.y = f2b(v.y); o.z = f2b(v.z); o.w = f2b(v.w);
    *(ushort4*)(out + i) = o;
}

__global__ __launch_bounds__(256) void cvt_w(const float* __restrict__ Wfc,
                                             const float* __restrict__ Wres,
                                             unsigned short* __restrict__ out)
{
    int i = (blockIdx.x * 256 + threadIdx.x) * 4;   // 131072 total
    float4 v = (i < 65536) ? *(const float4*)(Wfc + i)
                           : *(const float4*)(Wres + (i - 65536));
    ushort4 o;
    o.x = f2b(v.x); o.y = f2b(v.y); o.z = f2b(v.z); o.w = f2b(v.w);
    *(ushort4*)(out + i) = o;
}

// ---------------- bf16 MFMA dual GEMM (unchanged from R2) ----------------
__global__ __launch_bounds__(256) void gemm_mfma(
    const unsigned short* __restrict__ featb,   // [N][256] bf16
    const unsigned short* __restrict__ Wb,      // [512][256] bf16
    const float* __restrict__ bias,
    unsigned short* __restrict__ fsb,           // [N][256] bf16
    float* __restrict__ rst)                    // [N][256] fp32
{
    __shared__ __align__(16) char smem[32768];
    char* sA = smem;
    char* sB = smem + 16384;

    const int tid = threadIdx.x;
    const int w = tid >> 6, l = tid & 63;
    const int wm = w & 1, wn = w >> 1;
    const int row0 = blockIdx.x * 128;
    const int ny = blockIdx.y;

    f32x4 acc[4][4];
#pragma unroll
    for (int tm = 0; tm < 4; ++tm)
#pragma unroll
        for (int tn = 0; tn < 4; ++tn) acc[tm][tn] = (f32x4)0.f;

    const int srow = tid >> 3;
    const int sslot = tid & 7;

    for (int k0 = 0; k0 < 256; k0 += 64) {
        if (k0) __syncthreads();
#pragma unroll
        for (int it = 0; it < 4; ++it) {
            int r = srow + it * 32;
            int gr = row0 + r; if (gr >= NNODES) gr = NNODES - 1;
            int kc = sslot ^ (r & 7);
            const unsigned short* g = featb + (size_t)gr * 256 + k0 + kc * 8;
            void* sp = sA + (it * 256 + w * 64) * 16;
            __builtin_amdgcn_global_load_lds((glb_cvp)g, (lds_vp)sp, 16, 0, 0);
        }
#pragma unroll
        for (int it = 0; it < 4; ++it) {
            int r = srow + it * 32;
            int kc = sslot ^ (r & 7);
            const unsigned short* g = Wb + (size_t)(ny * 128 + r) * 256 + k0 + kc * 8;
            void* sp = sB + (it * 256 + w * 64) * 16;
            __builtin_amdgcn_global_load_lds((glb_cvp)g, (lds_vp)sp, 16, 0, 0);
        }
        __syncthreads();

        const int quad = l >> 4;
#pragma unroll
        for (int kk = 0; kk < 2; ++kk) {
            const int kc = kk * 4 + quad;
            bf16x8 af[4], bq[4];
#pragma unroll
            for (int tm = 0; tm < 4; ++tm) {
                int m = wm * 64 + tm * 16 + (l & 15);
                af[tm] = *(const bf16x8*)(sA + m * 128 + ((kc ^ (m & 7)) * 16));
            }
#pragma unroll
            for (int tn = 0; tn < 4; ++tn) {
                int n = wn * 64 + tn * 16 + (l & 15);
                bq[tn] = *(const bf16x8*)(sB + n * 128 + ((kc ^ (n & 7)) * 16));
            }
#pragma unroll
            for (int tm = 0; tm < 4; ++tm)
#pragma unroll
                for (int tn = 0; tn < 4; ++tn)
                    acc[tm][tn] = __builtin_amdgcn_mfma_f32_16x16x32_bf16(
                        af[tm], bq[tn], acc[tm][tn], 0, 0, 0);
        }
    }

    const int quad = l >> 4, c15 = l & 15;
    if (ny < 2) {
#pragma unroll
        for (int tm = 0; tm < 4; ++tm) {
            int rb = row0 + wm * 64 + tm * 16 + quad * 4;
#pragma unroll
            for (int tn = 0; tn < 4; ++tn) {
                int cg = ny * 128 + wn * 64 + tn * 16 + c15;
#pragma unroll
                for (int reg = 0; reg < 4; ++reg) {
                    int r = rb + reg;
                    if (r < NNODES) fsb[(size_t)r * 256 + cg] = f2b(acc[tm][tn][reg]);
                }
            }
        }
    } else {
#pragma unroll
        for (int tm = 0; tm < 4; ++tm) {
            int rb = row0 + wm * 64 + tm * 16 + quad * 4;
#pragma unroll
            for (int tn = 0; tn < 4; ++tn) {
                int co = (ny - 2) * 128 + wn * 64 + tn * 16 + c15;
                float b = bias[co];
#pragma unroll
                for (int reg = 0; reg < 4; ++reg) {
                    int r = rb + reg;
                    if (r < NNODES) rst[(size_t)r * 256 + co] = acc[tm][tn][reg] + b;
                }
            }
        }
    }
}

// ---------------- el/er: wave-per-node, ushort4 loads ----------------
__global__ __launch_bounds__(256) void eler_kernel(
    const unsigned short* __restrict__ fsb,
    const float* __restrict__ attn_l, const float* __restrict__ attn_r,
    float* __restrict__ el, float* __restrict__ er)
{
    const int tid = threadIdx.x;
    const int wv = tid >> 6, lane = tid & 63;
    const int n = blockIdx.x * 4 + wv;
    const int c0 = lane * 4;

    ushort4 v = *(const ushort4*)(fsb + (size_t)n * 256 + c0);
    float4 al = *(const float4*)(attn_l + c0);
    float4 ar = *(const float4*)(attn_r + c0);
    float f0 = b2f(v.x), f1 = b2f(v.y), f2 = b2f(v.z), f3 = b2f(v.w);
    float pl = f0 * al.x + f1 * al.y + f2 * al.z + f3 * al.w;
    float pr = f0 * ar.x + f1 * ar.y + f2 * ar.z + f3 * ar.w;
    // reduce within each 16-lane group (one head per group)
#pragma unroll
    for (int d = 1; d < 16; d <<= 1) {
        pl += __shfl_xor(pl, d);
        pr += __shfl_xor(pr, d);
    }
    if ((lane & 15) == 0) {
        int h = lane >> 4;
        el[n * NHEAD + h] = pl;
        er[n * NHEAD + h] = pr;
    }
}

// ---------------- CSR build (order-free grouping by dst) ----------------
__global__ __launch_bounds__(256) void count_kernel(const int* __restrict__ dst,
                                                    int* __restrict__ cnt)
{
    int e = blockIdx.x * 256 + threadIdx.x;
    if (e < NEDGES) atomicAdd(&cnt[dst[e]], 1);
}

__global__ __launch_bounds__(256) void offset_kernel(const int* __restrict__ cnt,
                                                     int* __restrict__ off,
                                                     int* __restrict__ cursor,
                                                     int* __restrict__ total)
{
    int n = blockIdx.x * 256 + threadIdx.x;
    if (n < NNODES) {
        int c = cnt[n];
        int o = atomicAdd(total, c);
        off[n] = o;
        cursor[n] = o;
    }
}

__global__ __launch_bounds__(256) void scatter_kernel(const int* __restrict__ dst,
                                                      int* __restrict__ cursor,
                                                      int* __restrict__ perm)
{
    int e = blockIdx.x * 256 + threadIdx.x;
    if (e < NEDGES) {
        int p = atomicAdd(&cursor[dst[e]], 1);
        perm[p] = e;
    }
}

// ---------------- agg: one wave per dst node ----------------
// Wave handles node n. Lane owns cols [lane*4, lane*4+4); head h = lane>>4.
// Sweep 1: online softmax (m,s) over edges, lanes parallel, shuffle-combine.
// Sweep 2: per-edge a via shuffle broadcast; ushort4 feature gather; fp32 acc.
__global__ __launch_bounds__(256) void agg_kernel(
    const int* __restrict__ src, const int* __restrict__ perm,
    const int* __restrict__ off, const int* __restrict__ cnt,
    const float* __restrict__ el, const float* __restrict__ er,
    const unsigned short* __restrict__ fsb,
    float* __restrict__ rst,
    float* __restrict__ m_arr, float* __restrict__ inv_arr)
{
    const int tid = threadIdx.x;
    const int wv = tid >> 6, lane = tid & 63;
    const int n = blockIdx.x * 4 + wv;
    const int deg = cnt[n];
    if (deg == 0) return;              // rst keeps residual
    const int o0 = off[n];
    const int h = lane >> 4;

    const float4 er4 = *(const float4*)(er + (size_t)n * NHEAD);

    // ---- sweep 1: online (m, s) ----
    float4 m = make_float4(-1e30f, -1e30f, -1e30f, -1e30f);
    float4 s = make_float4(0.f, 0.f, 0.f, 0.f);
    int s0_save = 0; float4 l0_save = m;   // chunk-0 regs reused in sweep 2

    for (int base = 0; base < deg; base += 64) {
        int i = base + lane;
        bool valid = i < deg;
        int e = perm[o0 + (valid ? i : deg - 1)];
        int sidx = src[e];
        float4 ev = *(const float4*)(el + (size_t)sidx * NHEAD);
        float4 l;
        l.x = lrelu(ev.x + er4.x); l.y = lrelu(ev.y + er4.y);
        l.z = lrelu(ev.z + er4.z); l.w = lrelu(ev.w + er4.w);
        if (base == 0) { s0_save = sidx; l0_save = l; }
        float mn;
        mn = fmaxf(m.x, l.x); s.x = s.x * __expf(m.x - mn) + (valid ? __expf(l.x - mn) : 0.f); m.x = mn;
        mn = fmaxf(m.y, l.y); s.y = s.y * __expf(m.y - mn) + (valid ? __expf(l.y - mn) : 0.f); m.y = mn;
        mn = fmaxf(m.z, l.z); s.z = s.z * __expf(m.z - mn) + (valid ? __expf(l.z - mn) : 0.f); m.z = mn;
        mn = fmaxf(m.w, l.w); s.w = s.w * __expf(m.w - mn) + (valid ? __expf(l.w - mn) : 0.f); m.w = mn;
    }
    // wave combine (xor butterfly): (m,s) <- merge((m,s),(mo,so))
#pragma unroll
    for (int d = 32; d > 0; d >>= 1) {
        float mo, so, mn;
        mo = __shfl_xor(m.x, d); so = __shfl_xor(s.x, d);
        mn = fmaxf(m.x, mo); s.x = s.x * __expf(m.x - mn) + so * __expf(mo - mn); m.x = mn;
        mo = __shfl_xor(m.y, d); so = __shfl_xor(s.y, d);
        mn = fmaxf(m.y, mo); s.y = s.y * __expf(m.y - mn) + so * __expf(mo - mn); m.y = mn;
        mo = __shfl_xor(m.z, d); so = __shfl_xor(s.z, d);
        mn = fmaxf(m.z, mo); s.z = s.z * __expf(m.z - mn) + so * __expf(mo - mn); m.z = mn;
        mo = __shfl_xor(m.w, d); so = __shfl_xor(s.w, d);
        mn = fmaxf(m.w, mo); s.w = s.w * __expf(m.w - mn) + so * __expf(mo - mn); m.w = mn;
    }
    float4 inv;
    inv.x = 1.f / fmaxf(s.x, 1e-20f);
    inv.y = 1.f / fmaxf(s.y, 1e-20f);
    inv.z = 1.f / fmaxf(s.z, 1e-20f);
    inv.w = 1.f / fmaxf(s.w, 1e-20f);
    if (lane == 0) {
        *(float4*)(m_arr + (size_t)n * NHEAD) = m;
        *(float4*)(inv_arr + (size_t)n * NHEAD) = inv;
    }

    // ---- sweep 2: a + feature accumulate ----
    float4 acc = make_float4(0.f, 0.f, 0.f, 0.f);
    for (int base = 0; base < deg; base += 64) {
        int i = base + lane;
        bool valid = i < deg;
        int sidx; float4 l;
        if (base == 0) { sidx = s0_save; l = l0_save; }
        else {
            int e = perm[o0 + (valid ? i : deg - 1)];
            sidx = src[e];
            float4 ev = *(const float4*)(el + (size_t)sidx * NHEAD);
            l.x = lrelu(ev.x + er4.x); l.y = lrelu(ev.y + er4.y);
            l.z = lrelu(ev.z + er4.z); l.w = lrelu(ev.w + er4.w);
        }
        float4 a;
        a.x = valid ? __expf(l.x - m.x) * inv.x : 0.f;
        a.y = valid ? __expf(l.y - m.y) * inv.y : 0.f;
        a.z = valid ? __expf(l.z - m.z) * inv.z : 0.f;
        a.w = valid ? __expf(l.w - m.w) * inv.w : 0.f;

        int nc = min(64, deg - base);
        for (int j = 0; j < nc; ++j) {
            int sj = __shfl(sidx, j);
            float ax = __shfl(a.x, j), ay = __shfl(a.y, j);
            float az = __shfl(a.z, j), aw = __shfl(a.w, j);
            float av = (h == 0) ? ax : (h == 1) ? ay : (h == 2) ? az : aw;
            uint2 p = *(const uint2*)(fsb + (size_t)sj * 256 + lane * 4);
            acc.x = fmaf(av, __uint_as_float(p.x << 16), acc.x);
            acc.y = fmaf(av, __uint_as_float(p.x & 0xffff0000u), acc.y);
            acc.z = fmaf(av, __uint_as_float(p.y << 16), acc.z);
            acc.w = fmaf(av, __uint_as_float(p.y & 0xffff0000u), acc.w);
        }
    }
    size_t ro = (size_t)n * 256 + lane * 4;
    float4 r = *(float4*)(rst + ro);
    r.x += acc.x; r.y += acc.y; r.z += acc.z; r.w += acc.w;
    *(float4*)(rst + ro) = r;
}

// ---------------- a_out: edge-parallel, coalesced writes ----------------
__global__ __launch_bounds__(256) void aout_kernel(
    const int* __restrict__ src, const int* __restrict__ dst,
    const float* __restrict__ el, const float* __restrict__ er,
    const float* __restrict__ m_arr, const float* __restrict__ inv_arr,
    float* __restrict__ a_out)
{
    int e = blockIdx.x * 256 + threadIdx.x;
    if (e >= NEDGES) return;
    int sidx = src[e], d = dst[e];
    float4 ev = *(const float4*)(el + (size_t)sidx * NHEAD);
    float4 rv = *(const float4*)(er + (size_t)d * NHEAD);
    float4 m4 = *(const float4*)(m_arr + (size_t)d * NHEAD);
    float4 i4 = *(const float4*)(inv_arr + (size_t)d * NHEAD);
    float4 a;
    a.x = __expf(lrelu(ev.x + rv.x) - m4.x) * i4.x;
    a.y = __expf(lrelu(ev.y + rv.y) - m4.y) * i4.y;
    a.z = __expf(lrelu(ev.z + rv.z) - m4.z) * i4.z;
    a.w = __expf(lrelu(ev.w + rv.w) - m4.w) * i4.w;
    *(float4*)(a_out + (size_t)e * NHEAD) = a;
}

// ---------------- launch ----------------
extern "C" void kernel_launch(void* const* d_in, const int* in_sizes, int n_in,
                              void* d_out, int out_size, void* d_ws, size_t ws_size,
                              hipStream_t stream) {
    const float* feat   = (const float*)d_in[0];
    const int*   src    = (const int*)d_in[1];
    const int*   dst    = (const int*)d_in[2];
    const float* Wfc    = (const float*)d_in[3];
    const float* attn_l = (const float*)d_in[4];
    const float* attn_r = (const float*)d_in[5];
    const float* Wres   = (const float*)d_in[6];
    const float* bias   = (const float*)d_in[7];

    float* rst   = (float*)d_out;                              // N*256
    float* a_out = (float*)d_out + (size_t)NNODES * CDIM;      // E*4

    // workspace layout (~117 MB)
    unsigned short* featb = (unsigned short*)d_ws;             // N*256 bf16
    unsigned short* fsb   = featb + (size_t)NNODES * CDIM;     // N*256 bf16
    unsigned short* Wb    = fsb + (size_t)NNODES * CDIM;       // 512*256 bf16
    float* el      = (float*)(Wb + 512 * 256);                 // N*4
    float* er      = el + (size_t)NNODES * NHEAD;              // N*4
    float* m_arr   = er + (size_t)NNODES * NHEAD;              // N*4
    float* inv_arr = m_arr + (size_t)NNODES * NHEAD;           // N*4
    int* cnt    = (int*)(inv_arr + (size_t)NNODES * NHEAD);    // N
    int* off    = cnt + NNODES;                                // N
    int* cursor = off + NNODES;                                // N
    int* total  = cursor + NNODES;                             // 4
    int* perm   = total + 4;                                   // E

    hipMemsetAsync(cnt, 0, NNODES * sizeof(int), stream);
    hipMemsetAsync(total, 0, 4 * sizeof(int), stream);

    cvt_feat<<<(NNODES * CDIM) / (256 * 4), 256, 0, stream>>>(feat, featb);
    cvt_w<<<(512 * 256) / (256 * 4), 256, 0, stream>>>(Wfc, Wres, Wb);

    dim3 ggrid((NNODES + 127) / 128, 4);
    gemm_mfma<<<ggrid, 256, 0, stream>>>(featb, Wb, bias, fsb, rst);

    eler_kernel<<<NNODES / 4, 256, 0, stream>>>(fsb, attn_l, attn_r, el, er);

    count_kernel<<<(NEDGES + 255) / 256, 256, 0, stream>>>(dst, cnt);
    offset_kernel<<<(NNODES + 255) / 256, 256, 0, stream>>>(cnt, off, cursor, total);
    scatter_kernel<<<(NEDGES + 255) / 256, 256, 0, stream>>>(dst, cursor, perm);

    agg_kernel<<<NNODES / 4, 256, 0, stream>>>(src, perm, off, cnt, el, er,
                                               fsb, rst, m_arr, inv_arr);
    aout_kernel<<<(NEDGES + 255) / 256, 256, 0, stream>>>(src, dst, el, er,
                                                          m_arr, inv_arr, a_out);
}

// Round 4
// 724.638 us; speedup vs baseline: 2.0580x; 1.0232x over previous
//
#include <hip/hip_runtime.h>

// ---------------- problem constants ----------------
#define NNODES 100000
#define NEDGES 1600000
#define KDIM 256          // IN
#define CDIM 256          // H*F
#define NHEAD 4
#define FDIM 64
#define NEG 0.05f

typedef short bf16x8 __attribute__((ext_vector_type(8)));   // 8 bf16 in 4 VGPRs
typedef float f32x4  __attribute__((ext_vector_type(4)));
typedef __attribute__((address_space(3))) void*       lds_vp;
typedef __attribute__((address_space(1))) const void* glb_cvp;

__device__ __forceinline__ unsigned short f2b(float x) {   // fp32 -> bf16 RNE
    unsigned int u = __float_as_uint(x);
    return (unsigned short)((u + 0x7FFFu + ((u >> 16) & 1u)) >> 16);
}
__device__ __forceinline__ float b2f(unsigned short b) {
    return __uint_as_float(((unsigned int)b) << 16);
}
__device__ __forceinline__ float lrelu(float x) { return x > 0.f ? x : NEG * x; }

// ---------------- fp32 -> bf16 converts ----------------
__global__ __launch_bounds__(256) void cvt_feat(const float* __restrict__ in,
                                                unsigned short* __restrict__ out)
{
    int i = (blockIdx.x * 256 + threadIdx.x) * 4;
    float4 v = *(const float4*)(in + i);
    ushort4 o;
    o.x = f2b(v.x); o.y = f2b(v.y); o.z = f2b(v.z); o.w = f2b(v.w);
    *(ushort4*)(out + i) = o;
}

__global__ __launch_bounds__(256) void cvt_w(const float* __restrict__ Wfc,
                                             const float* __restrict__ Wres,
                                             unsigned short* __restrict__ out)
{
    int i = (blockIdx.x * 256 + threadIdx.x) * 4;   // 131072 total
    float4 v = (i < 65536) ? *(const float4*)(Wfc + i)
                           : *(const float4*)(Wres + (i - 65536));
    ushort4 o;
    o.x = f2b(v.x); o.y = f2b(v.y); o.z = f2b(v.z); o.w = f2b(v.w);
    *(ushort4*)(out + i) = o;
}

// ---------------- bf16 MFMA dual GEMM ----------------
// XCD-affinity swizzle: the 4 ny-siblings of one row-block are spaced 8 apart
// in dispatch index (same XCD under round-robin) and within one 32-block
// window -> A-tile is fetched once per XCD L2 instead of 4x from HBM.
__global__ __launch_bounds__(256) void gemm_mfma(
    const unsigned short* __restrict__ featb,   // [N][256] bf16
    const unsigned short* __restrict__ Wb,      // [512][256] bf16
    const float* __restrict__ bias,
    unsigned short* __restrict__ fsb,           // [N][256] bf16
    float* __restrict__ rst)                    // [N][256] fp32
{
    const int b = blockIdx.x;
    const int grp = b >> 5, w32 = b & 31;
    const int bx = grp * 8 + (w32 & 7);
    const int ny = w32 >> 3;
    if (bx >= (NNODES + 127) / 128) return;

    __shared__ __align__(16) char smem[32768];
    char* sA = smem;
    char* sB = smem + 16384;

    const int tid = threadIdx.x;
    const int w = tid >> 6, l = tid & 63;
    const int wm = w & 1, wn = w >> 1;
    const int row0 = bx * 128;

    f32x4 acc[4][4];
#pragma unroll
    for (int tm = 0; tm < 4; ++tm)
#pragma unroll
        for (int tn = 0; tn < 4; ++tn) acc[tm][tn] = (f32x4)0.f;

    const int srow = tid >> 3;
    const int sslot = tid & 7;

    for (int k0 = 0; k0 < 256; k0 += 64) {
        if (k0) __syncthreads();
#pragma unroll
        for (int it = 0; it < 4; ++it) {
            int r = srow + it * 32;
            int gr = row0 + r; if (gr >= NNODES) gr = NNODES - 1;
            int kc = sslot ^ (r & 7);
            const unsigned short* g = featb + (size_t)gr * 256 + k0 + kc * 8;
            void* sp = sA + (it * 256 + w * 64) * 16;
            __builtin_amdgcn_global_load_lds((glb_cvp)g, (lds_vp)sp, 16, 0, 0);
        }
#pragma unroll
        for (int it = 0; it < 4; ++it) {
            int r = srow + it * 32;
            int kc = sslot ^ (r & 7);
            const unsigned short* g = Wb + (size_t)(ny * 128 + r) * 256 + k0 + kc * 8;
            void* sp = sB + (it * 256 + w * 64) * 16;
            __builtin_amdgcn_global_load_lds((glb_cvp)g, (lds_vp)sp, 16, 0, 0);
        }
        __syncthreads();

        const int quad = l >> 4;
#pragma unroll
        for (int kk = 0; kk < 2; ++kk) {
            const int kc = kk * 4 + quad;
            bf16x8 af[4], bq[4];
#pragma unroll
            for (int tm = 0; tm < 4; ++tm) {
                int m = wm * 64 + tm * 16 + (l & 15);
                af[tm] = *(const bf16x8*)(sA + m * 128 + ((kc ^ (m & 7)) * 16));
            }
#pragma unroll
            for (int tn = 0; tn < 4; ++tn) {
                int n = wn * 64 + tn * 16 + (l & 15);
                bq[tn] = *(const bf16x8*)(sB + n * 128 + ((kc ^ (n & 7)) * 16));
            }
#pragma unroll
            for (int tm = 0; tm < 4; ++tm)
#pragma unroll
                for (int tn = 0; tn < 4; ++tn)
                    acc[tm][tn] = __builtin_amdgcn_mfma_f32_16x16x32_bf16(
                        af[tm], bq[tn], acc[tm][tn], 0, 0, 0);
        }
    }

    const int quad = l >> 4, c15 = l & 15;
    if (ny < 2) {
#pragma unroll
        for (int tm = 0; tm < 4; ++tm) {
            int rb = row0 + wm * 64 + tm * 16 + quad * 4;
#pragma unroll
            for (int tn = 0; tn < 4; ++tn) {
                int cg = ny * 128 + wn * 64 + tn * 16 + c15;
#pragma unroll
                for (int reg = 0; reg < 4; ++reg) {
                    int r = rb + reg;
                    if (r < NNODES) fsb[(size_t)r * 256 + cg] = f2b(acc[tm][tn][reg]);
                }
            }
        }
    } else {
#pragma unroll
        for (int tm = 0; tm < 4; ++tm) {
            int rb = row0 + wm * 64 + tm * 16 + quad * 4;
#pragma unroll
            for (int tn = 0; tn < 4; ++tn) {
                int co = (ny - 2) * 128 + wn * 64 + tn * 16 + c15;
                float b2 = bias[co];
#pragma unroll
                for (int reg = 0; reg < 4; ++reg) {
                    int r = rb + reg;
                    if (r < NNODES) rst[(size_t)r * 256 + co] = acc[tm][tn][reg] + b2;
                }
            }
        }
    }
}

// ---------------- el/er: wave-per-node, ushort4 loads ----------------
__global__ __launch_bounds__(256) void eler_kernel(
    const unsigned short* __restrict__ fsb,
    const float* __restrict__ attn_l, const float* __restrict__ attn_r,
    float* __restrict__ el, float* __restrict__ er)
{
    const int tid = threadIdx.x;
    const int wv = tid >> 6, lane = tid & 63;
    const int n = blockIdx.x * 4 + wv;
    const int c0 = lane * 4;

    ushort4 v = *(const ushort4*)(fsb + (size_t)n * 256 + c0);
    float4 al = *(const float4*)(attn_l + c0);
    float4 ar = *(const float4*)(attn_r + c0);
    float f0 = b2f(v.x), f1 = b2f(v.y), f2 = b2f(v.z), f3 = b2f(v.w);
    float pl = f0 * al.x + f1 * al.y + f2 * al.z + f3 * al.w;
    float pr = f0 * ar.x + f1 * ar.y + f2 * ar.z + f3 * ar.w;
#pragma unroll
    for (int d = 1; d < 16; d <<= 1) {
        pl += __shfl_xor(pl, d);
        pr += __shfl_xor(pr, d);
    }
    if ((lane & 15) == 0) {
        int h = lane >> 4;
        el[n * NHEAD + h] = pl;
        er[n * NHEAD + h] = pr;
    }
}

// ---------------- CSR build (order-free grouping by dst) ----------------
__global__ __launch_bounds__(256) void count_kernel(const int* __restrict__ dst,
                                                    int* __restrict__ cnt)
{
    int e = blockIdx.x * 256 + threadIdx.x;
    if (e < NEDGES) atomicAdd(&cnt[dst[e]], 1);
}

__global__ __launch_bounds__(256) void offset_kernel(const int* __restrict__ cnt,
                                                     int* __restrict__ off,
                                                     int* __restrict__ cursor,
                                                     int* __restrict__ total)
{
    int n = blockIdx.x * 256 + threadIdx.x;
    if (n < NNODES) {
        int c = cnt[n];
        int o = atomicAdd(total, c);
        off[n] = o;
        cursor[n] = o;
    }
}

__global__ __launch_bounds__(256) void scatter_kernel(const int* __restrict__ dst,
                                                      int* __restrict__ cursor,
                                                      int* __restrict__ perm)
{
    int e = blockIdx.x * 256 + threadIdx.x;
    if (e < NEDGES) {
        int p = atomicAdd(&cursor[dst[e]], 1);
        perm[p] = e;
    }
}

// ---------------- agg: one wave per dst node ----------------
// Sweep 1: online softmax (m,s), lanes parallel over edges, xor-combine.
// Sweep 2: stage (a, src) per 64-edge chunk in wave-private LDS; inner loop
// reads a via broadcast ds_read, src via ds_read+readfirstlane -> scalar row
// address -> saddr global_load_dwordx2 with loop-invariant lane offset.
__global__ __launch_bounds__(256) void agg_kernel(
    const int* __restrict__ src, const int* __restrict__ perm,
    const int* __restrict__ off, const int* __restrict__ cnt,
    const float* __restrict__ el, const float* __restrict__ er,
    const unsigned short* __restrict__ fsb,
    float* __restrict__ rst,
    float* __restrict__ m_arr, float* __restrict__ inv_arr)
{
    const int tid = threadIdx.x;
    const int wv = tid >> 6, lane = tid & 63;
    const int n = blockIdx.x * 4 + wv;
    const int deg = cnt[n];
    if (deg == 0) return;              // rst keeps residual
    const int o0 = off[n];
    const int h = lane >> 4;

    __shared__ __align__(16) float a_sh[4][64][4];
    __shared__ int s_sh[4][64];
    float* aw = &a_sh[wv][0][0];
    int*   sw = &s_sh[wv][0];

    const float4 er4 = *(const float4*)(er + (size_t)n * NHEAD);

    // ---- sweep 1: online (m, s) ----
    float4 m = make_float4(-1e30f, -1e30f, -1e30f, -1e30f);
    float4 s = make_float4(0.f, 0.f, 0.f, 0.f);
    int s0_save = 0; float4 l0_save = m;

    for (int base = 0; base < deg; base += 64) {
        int i = base + lane;
        bool valid = i < deg;
        int e = perm[o0 + (valid ? i : deg - 1)];
        int sidx = src[e];
        float4 ev = *(const float4*)(el + (size_t)sidx * NHEAD);
        float4 l;
        l.x = lrelu(ev.x + er4.x); l.y = lrelu(ev.y + er4.y);
        l.z = lrelu(ev.z + er4.z); l.w = lrelu(ev.w + er4.w);
        if (base == 0) { s0_save = sidx; l0_save = l; }
        float mn;
        mn = fmaxf(m.x, l.x); s.x = s.x * __expf(m.x - mn) + (valid ? __expf(l.x - mn) : 0.f); m.x = mn;
        mn = fmaxf(m.y, l.y); s.y = s.y * __expf(m.y - mn) + (valid ? __expf(l.y - mn) : 0.f); m.y = mn;
        mn = fmaxf(m.z, l.z); s.z = s.z * __expf(m.z - mn) + (valid ? __expf(l.z - mn) : 0.f); m.z = mn;
        mn = fmaxf(m.w, l.w); s.w = s.w * __expf(m.w - mn) + (valid ? __expf(l.w - mn) : 0.f); m.w = mn;
    }
#pragma unroll
    for (int d = 32; d > 0; d >>= 1) {
        float mo, so, mn;
        mo = __shfl_xor(m.x, d); so = __shfl_xor(s.x, d);
        mn = fmaxf(m.x, mo); s.x = s.x * __expf(m.x - mn) + so * __expf(mo - mn); m.x = mn;
        mo = __shfl_xor(m.y, d); so = __shfl_xor(s.y, d);
        mn = fmaxf(m.y, mo); s.y = s.y * __expf(m.y - mn) + so * __expf(mo - mn); m.y = mn;
        mo = __shfl_xor(m.z, d); so = __shfl_xor(s.z, d);
        mn = fmaxf(m.z, mo); s.z = s.z * __expf(m.z - mn) + so * __expf(mo - mn); m.z = mn;
        mo = __shfl_xor(m.w, d); so = __shfl_xor(s.w, d);
        mn = fmaxf(m.w, mo); s.w = s.w * __expf(m.w - mn) + so * __expf(mo - mn); m.w = mn;
    }
    float4 inv;
    inv.x = 1.f / fmaxf(s.x, 1e-20f);
    inv.y = 1.f / fmaxf(s.y, 1e-20f);
    inv.z = 1.f / fmaxf(s.z, 1e-20f);
    inv.w = 1.f / fmaxf(s.w, 1e-20f);
    if (lane == 0) {
        *(float4*)(m_arr + (size_t)n * NHEAD) = m;
        *(float4*)(inv_arr + (size_t)n * NHEAD) = inv;
    }

    // ---- sweep 2: LDS-staged a/src + scalar-addressed gather ----
    float4 acc = make_float4(0.f, 0.f, 0.f, 0.f);
    const int laneoff = lane << 2;          // ushort index; 8B per lane
    for (int base = 0; base < deg; base += 64) {
        int i = base + lane;
        bool valid = i < deg;
        int sidx; float4 l;
        if (base == 0) { sidx = s0_save; l = l0_save; }
        else {
            int e = perm[o0 + (valid ? i : deg - 1)];
            sidx = src[e];
            float4 ev = *(const float4*)(el + (size_t)sidx * NHEAD);
            l.x = lrelu(ev.x + er4.x); l.y = lrelu(ev.y + er4.y);
            l.z = lrelu(ev.z + er4.z); l.w = lrelu(ev.w + er4.w);
        }
        float4 a;
        a.x = valid ? __expf(l.x - m.x) * inv.x : 0.f;
        a.y = valid ? __expf(l.y - m.y) * inv.y : 0.f;
        a.z = valid ? __expf(l.z - m.z) * inv.z : 0.f;
        a.w = valid ? __expf(l.w - m.w) * inv.w : 0.f;
        *(float4*)(aw + (lane << 2)) = a;   // wave-synchronous staging
        sw[lane] = sidx;

        int nc = min(64, deg - base);
#pragma unroll 4
        for (int j = 0; j < nc; ++j) {
            float av = aw[(j << 2) + h];                       // broadcast ds_read
            int sj = __builtin_amdgcn_readfirstlane(sw[j]);    // uniform -> SGPR
            const unsigned short* rp = fsb + ((size_t)sj << 8) + laneoff;
            uint2 p = *(const uint2*)rp;                       // saddr + lane voff
            acc.x = fmaf(av, __uint_as_float(p.x << 16), acc.x);
            acc.y = fmaf(av, __uint_as_float(p.x & 0xffff0000u), acc.y);
            acc.z = fmaf(av, __uint_as_float(p.y << 16), acc.z);
            acc.w = fmaf(av, __uint_as_float(p.y & 0xffff0000u), acc.w);
        }
    }
    size_t ro = (size_t)n * 256 + (lane << 2);
    float4 r = *(float4*)(rst + ro);
    r.x += acc.x; r.y += acc.y; r.z += acc.z; r.w += acc.w;
    *(float4*)(rst + ro) = r;
}

// ---------------- a_out: edge-parallel, coalesced writes ----------------
__global__ __launch_bounds__(256) void aout_kernel(
    const int* __restrict__ src, const int* __restrict__ dst,
    const float* __restrict__ el, const float* __restrict__ er,
    const float* __restrict__ m_arr, const float* __restrict__ inv_arr,
    float* __restrict__ a_out)
{
    int e = blockIdx.x * 256 + threadIdx.x;
    if (e >= NEDGES) return;
    int sidx = src[e], d = dst[e];
    float4 ev = *(const float4*)(el + (size_t)sidx * NHEAD);
    float4 rv = *(const float4*)(er + (size_t)d * NHEAD);
    float4 m4 = *(const float4*)(m_arr + (size_t)d * NHEAD);
    float4 i4 = *(const float4*)(inv_arr + (size_t)d * NHEAD);
    float4 a;
    a.x = __expf(lrelu(ev.x + rv.x) - m4.x) * i4.x;
    a.y = __expf(lrelu(ev.y + rv.y) - m4.y) * i4.y;
    a.z = __expf(lrelu(ev.z + rv.z) - m4.z) * i4.z;
    a.w = __expf(lrelu(ev.w + rv.w) - m4.w) * i4.w;
    *(float4*)(a_out + (size_t)e * NHEAD) = a;
}

// ---------------- launch ----------------
extern "C" void kernel_launch(void* const* d_in, const int* in_sizes, int n_in,
                              void* d_out, int out_size, void* d_ws, size_t ws_size,
                              hipStream_t stream) {
    const float* feat   = (const float*)d_in[0];
    const int*   src    = (const int*)d_in[1];
    const int*   dst    = (const int*)d_in[2];
    const float* Wfc    = (const float*)d_in[3];
    const float* attn_l = (const float*)d_in[4];
    const float* attn_r = (const float*)d_in[5];
    const float* Wres   = (const float*)d_in[6];
    const float* bias   = (const float*)d_in[7];

    float* rst   = (float*)d_out;                              // N*256
    float* a_out = (float*)d_out + (size_t)NNODES * CDIM;      // E*4

    unsigned short* featb = (unsigned short*)d_ws;             // N*256 bf16
    unsigned short* fsb   = featb + (size_t)NNODES * CDIM;     // N*256 bf16
    unsigned short* Wb    = fsb + (size_t)NNODES * CDIM;       // 512*256 bf16
    float* el      = (float*)(Wb + 512 * 256);                 // N*4
    float* er      = el + (size_t)NNODES * NHEAD;              // N*4
    float* m_arr   = er + (size_t)NNODES * NHEAD;              // N*4
    float* inv_arr = m_arr + (size_t)NNODES * NHEAD;           // N*4
    int* cnt    = (int*)(inv_arr + (size_t)NNODES * NHEAD);    // N
    int* off    = cnt + NNODES;                                // N
    int* cursor = off + NNODES;                                // N
    int* total  = cursor + NNODES;                             // 4
    int* perm   = total + 4;                                   // E

    hipMemsetAsync(cnt, 0, NNODES * sizeof(int), stream);
    hipMemsetAsync(total, 0, 4 * sizeof(int), stream);

    cvt_feat<<<(NNODES * CDIM) / (256 * 4), 256, 0, stream>>>(feat, featb);
    cvt_w<<<(512 * 256) / (256 * 4), 256, 0, stream>>>(Wfc, Wres, Wb);

    // 782 row-blocks -> 98 groups of 8 -> grid 98*32 = 3136 (tail guarded)
    gemm_mfma<<<3136, 256, 0, stream>>>(featb, Wb, bias, fsb, rst);

    eler_kernel<<<NNODES / 4, 256, 0, stream>>>(fsb, attn_l, attn_r, el, er);

    count_kernel<<<(NEDGES + 255) / 256, 256, 0, stream>>>(dst, cnt);
    offset_kernel<<<(NNODES + 255) / 256, 256, 0, stream>>>(cnt, off, cursor, total);
    scatter_kernel<<<(NEDGES + 255) / 256, 256, 0, stream>>>(dst, cursor, perm);

    agg_kernel<<<NNODES / 4, 256, 0, stream>>>(src, perm, off, cnt, el, er,
                                               fsb, rst, m_arr, inv_arr);
    aout_kernel<<<(NEDGES + 255) / 256, 256, 0, stream>>>(src, dst, el, er,
                                                          m_arr, inv_arr, a_out);
}

// Round 5
// 721.442 us; speedup vs baseline: 2.0671x; 1.0044x over previous
//
#include <hip/hip_runtime.h>

// ---------------- problem constants ----------------
#define NNODES 100000
#define NEDGES 1600000
#define KDIM 256          // IN
#define CDIM 256          // H*F
#define NHEAD 4
#define FDIM 64
#define NEG 0.05f

typedef short bf16x8 __attribute__((ext_vector_type(8)));   // 8 bf16 in 4 VGPRs
typedef float f32x4  __attribute__((ext_vector_type(4)));
typedef __attribute__((address_space(3))) void*       lds_vp;
typedef __attribute__((address_space(1))) const void* glb_cvp;

__device__ __forceinline__ unsigned short f2b(float x) {   // fp32 -> bf16 RNE
    unsigned int u = __float_as_uint(x);
    return (unsigned short)((u + 0x7FFFu + ((u >> 16) & 1u)) >> 16);
}
__device__ __forceinline__ float b2f(unsigned short b) {
    return __uint_as_float(((unsigned int)b) << 16);
}
__device__ __forceinline__ float lrelu(float x) { return x > 0.f ? x : NEG * x; }

// ---------------- fp32 -> bf16 converts ----------------
__global__ __launch_bounds__(256) void cvt_feat(const float* __restrict__ in,
                                                unsigned short* __restrict__ out)
{
    int i = (blockIdx.x * 256 + threadIdx.x) * 4;
    float4 v = *(const float4*)(in + i);
    ushort4 o;
    o.x = f2b(v.x); o.y = f2b(v.y); o.z = f2b(v.z); o.w = f2b(v.w);
    *(ushort4*)(out + i) = o;
}

__global__ __launch_bounds__(256) void cvt_w(const float* __restrict__ Wfc,
                                             const float* __restrict__ Wres,
                                             unsigned short* __restrict__ out)
{
    int i = (blockIdx.x * 256 + threadIdx.x) * 4;   // 131072 total
    float4 v = (i < 65536) ? *(const float4*)(Wfc + i)
                           : *(const float4*)(Wres + (i - 65536));
    ushort4 o;
    o.x = f2b(v.x); o.y = f2b(v.y); o.z = f2b(v.z); o.w = f2b(v.w);
    *(ushort4*)(out + i) = o;
}

// ---------------- bf16 MFMA dual GEMM + fused el/er epilogue ----------------
// XCD-affinity swizzle: the 4 ny-siblings of one row-block are spaced 8 apart
// in dispatch index (same XCD under round-robin) -> A-tile reused in XCD L2.
// For ny<2, each wave owns exactly one head's 64 columns, so el/er are
// computed from the fp32 accumulators and stored directly (no extra pass).
__global__ __launch_bounds__(256) void gemm_mfma(
    const unsigned short* __restrict__ featb,   // [N][256] bf16
    const unsigned short* __restrict__ Wb,      // [512][256] bf16
    const float* __restrict__ bias,
    const float* __restrict__ attn_l, const float* __restrict__ attn_r,
    unsigned short* __restrict__ fsb,           // [N][256] bf16
    float* __restrict__ rst,                    // [N][256] fp32
    float* __restrict__ el, float* __restrict__ er)
{
    const int b = blockIdx.x;
    const int grp = b >> 5, w32 = b & 31;
    const int bx = grp * 8 + (w32 & 7);
    const int ny = w32 >> 3;
    if (bx >= (NNODES + 127) / 128) return;

    __shared__ __align__(16) char smem[32768];
    char* sA = smem;
    char* sB = smem + 16384;

    const int tid = threadIdx.x;
    const int w = tid >> 6, l = tid & 63;
    const int wm = w & 1, wn = w >> 1;
    const int row0 = bx * 128;

    f32x4 acc[4][4];
#pragma unroll
    for (int tm = 0; tm < 4; ++tm)
#pragma unroll
        for (int tn = 0; tn < 4; ++tn) acc[tm][tn] = (f32x4)0.f;

    const int srow = tid >> 3;
    const int sslot = tid & 7;

    for (int k0 = 0; k0 < 256; k0 += 64) {
        if (k0) __syncthreads();
#pragma unroll
        for (int it = 0; it < 4; ++it) {
            int r = srow + it * 32;
            int gr = row0 + r; if (gr >= NNODES) gr = NNODES - 1;
            int kc = sslot ^ (r & 7);
            const unsigned short* g = featb + (size_t)gr * 256 + k0 + kc * 8;
            void* sp = sA + (it * 256 + w * 64) * 16;
            __builtin_amdgcn_global_load_lds((glb_cvp)g, (lds_vp)sp, 16, 0, 0);
        }
#pragma unroll
        for (int it = 0; it < 4; ++it) {
            int r = srow + it * 32;
            int kc = sslot ^ (r & 7);
            const unsigned short* g = Wb + (size_t)(ny * 128 + r) * 256 + k0 + kc * 8;
            void* sp = sB + (it * 256 + w * 64) * 16;
            __builtin_amdgcn_global_load_lds((glb_cvp)g, (lds_vp)sp, 16, 0, 0);
        }
        __syncthreads();

        const int quad = l >> 4;
#pragma unroll
        for (int kk = 0; kk < 2; ++kk) {
            const int kc = kk * 4 + quad;
            bf16x8 af[4], bq[4];
#pragma unroll
            for (int tm = 0; tm < 4; ++tm) {
                int m = wm * 64 + tm * 16 + (l & 15);
                af[tm] = *(const bf16x8*)(sA + m * 128 + ((kc ^ (m & 7)) * 16));
            }
#pragma unroll
            for (int tn = 0; tn < 4; ++tn) {
                int n = wn * 64 + tn * 16 + (l & 15);
                bq[tn] = *(const bf16x8*)(sB + n * 128 + ((kc ^ (n & 7)) * 16));
            }
#pragma unroll
            for (int tm = 0; tm < 4; ++tm)
#pragma unroll
                for (int tn = 0; tn < 4; ++tn)
                    acc[tm][tn] = __builtin_amdgcn_mfma_f32_16x16x32_bf16(
                        af[tm], bq[tn], acc[tm][tn], 0, 0, 0);
        }
    }

    const int quad = l >> 4, c15 = l & 15;
    if (ny < 2) {
        // ---- fsb stores ----
#pragma unroll
        for (int tm = 0; tm < 4; ++tm) {
            int rb = row0 + wm * 64 + tm * 16 + quad * 4;
#pragma unroll
            for (int tn = 0; tn < 4; ++tn) {
                int cg = ny * 128 + wn * 64 + tn * 16 + c15;
#pragma unroll
                for (int reg = 0; reg < 4; ++reg) {
                    int r = rb + reg;
                    if (r < NNODES) fsb[(size_t)r * 256 + cg] = f2b(acc[tm][tn][reg]);
                }
            }
        }
        // ---- fused el/er: this wave owns head hh's full 64 columns ----
        const int hh = ny * 2 + wn;
        float alv[4], arv[4];
#pragma unroll
        for (int tn = 0; tn < 4; ++tn) {
            alv[tn] = attn_l[hh * 64 + tn * 16 + c15];
            arv[tn] = attn_r[hh * 64 + tn * 16 + c15];
        }
#pragma unroll
        for (int tm = 0; tm < 4; ++tm) {
#pragma unroll
            for (int reg = 0; reg < 4; ++reg) {
                float pl = 0.f, pr = 0.f;
#pragma unroll
                for (int tn = 0; tn < 4; ++tn) {
                    float v = acc[tm][tn][reg];
                    pl = fmaf(v, alv[tn], pl);
                    pr = fmaf(v, arv[tn], pr);
                }
#pragma unroll
                for (int d = 1; d < 16; d <<= 1) {
                    pl += __shfl_xor(pl, d);
                    pr += __shfl_xor(pr, d);
                }
                if (c15 == 0) {
                    int r = row0 + wm * 64 + tm * 16 + quad * 4 + reg;
                    if (r < NNODES) {
                        el[r * NHEAD + hh] = pl;
                        er[r * NHEAD + hh] = pr;
                    }
                }
            }
        }
    } else {
#pragma unroll
        for (int tm = 0; tm < 4; ++tm) {
            int rb = row0 + wm * 64 + tm * 16 + quad * 4;
#pragma unroll
            for (int tn = 0; tn < 4; ++tn) {
                int co = (ny - 2) * 128 + wn * 64 + tn * 16 + c15;
                float b2 = bias[co];
#pragma unroll
                for (int reg = 0; reg < 4; ++reg) {
                    int r = rb + reg;
                    if (r < NNODES) rst[(size_t)r * 256 + co] = acc[tm][tn][reg] + b2;
                }
            }
        }
    }
}

// ---------------- CSR build (order-free grouping by dst) ----------------
__global__ __launch_bounds__(256) void count_kernel(const int* __restrict__ dst,
                                                    int* __restrict__ cnt)
{
    int e = blockIdx.x * 256 + threadIdx.x;
    if (e < NEDGES) atomicAdd(&cnt[dst[e]], 1);
}

__global__ __launch_bounds__(256) void offset_kernel(const int* __restrict__ cnt,
                                                     int* __restrict__ off,
                                                     int* __restrict__ cursor,
                                                     int* __restrict__ total)
{
    int n = blockIdx.x * 256 + threadIdx.x;
    if (n < NNODES) {
        int c = cnt[n];
        int o = atomicAdd(total, c);
        off[n] = o;
        cursor[n] = o;
    }
}

__global__ __launch_bounds__(256) void scatter_kernel(const int* __restrict__ dst,
                                                      int* __restrict__ cursor,
                                                      int* __restrict__ perm)
{
    int e = blockIdx.x * 256 + threadIdx.x;
    if (e < NEDGES) {
        int p = atomicAdd(&cursor[dst[e]], 1);
        perm[p] = e;
    }
}

// ---------------- agg: one wave per dst node ----------------
// Sweep 2 inner loop: sj broadcast via v_readlane from register (no LDS
// round-trip), a via broadcast ds_read, saddr-form 8B gather, unroll 8 for
// more loads in flight.
__global__ __launch_bounds__(256) void agg_kernel(
    const int* __restrict__ src, const int* __restrict__ perm,
    const int* __restrict__ off, const int* __restrict__ cnt,
    const float* __restrict__ el, const float* __restrict__ er,
    const unsigned short* __restrict__ fsb,
    float* __restrict__ rst,
    float* __restrict__ m_arr, float* __restrict__ inv_arr)
{
    const int tid = threadIdx.x;
    const int wv = tid >> 6, lane = tid & 63;
    const int n = blockIdx.x * 4 + wv;
    const int deg = cnt[n];
    if (deg == 0) return;              // rst keeps residual
    const int o0 = off[n];
    const int h = lane >> 4;

    __shared__ __align__(16) float a_sh[4][64][4];
    float* aw = &a_sh[wv][0][0];

    const float4 er4 = *(const float4*)(er + (size_t)n * NHEAD);

    // ---- sweep 1: online (m, s) ----
    float4 m = make_float4(-1e30f, -1e30f, -1e30f, -1e30f);
    float4 s = make_float4(0.f, 0.f, 0.f, 0.f);
    int s0_save = 0; float4 l0_save = m;

    for (int base = 0; base < deg; base += 64) {
        int i = base + lane;
        bool valid = i < deg;
        int e = perm[o0 + (valid ? i : deg - 1)];
        int sidx = src[e];
        float4 ev = *(const float4*)(el + (size_t)sidx * NHEAD);
        float4 l;
        l.x = lrelu(ev.x + er4.x); l.y = lrelu(ev.y + er4.y);
        l.z = lrelu(ev.z + er4.z); l.w = lrelu(ev.w + er4.w);
        if (base == 0) { s0_save = sidx; l0_save = l; }
        float mn;
        mn = fmaxf(m.x, l.x); s.x = s.x * __expf(m.x - mn) + (valid ? __expf(l.x - mn) : 0.f); m.x = mn;
        mn = fmaxf(m.y, l.y); s.y = s.y * __expf(m.y - mn) + (valid ? __expf(l.y - mn) : 0.f); m.y = mn;
        mn = fmaxf(m.z, l.z); s.z = s.z * __expf(m.z - mn) + (valid ? __expf(l.z - mn) : 0.f); m.z = mn;
        mn = fmaxf(m.w, l.w); s.w = s.w * __expf(m.w - mn) + (valid ? __expf(l.w - mn) : 0.f); m.w = mn;
    }
#pragma unroll
    for (int d = 32; d > 0; d >>= 1) {
        float mo, so, mn;
        mo = __shfl_xor(m.x, d); so = __shfl_xor(s.x, d);
        mn = fmaxf(m.x, mo); s.x = s.x * __expf(m.x - mn) + so * __expf(mo - mn); m.x = mn;
        mo = __shfl_xor(m.y, d); so = __shfl_xor(s.y, d);
        mn = fmaxf(m.y, mo); s.y = s.y * __expf(m.y - mn) + so * __expf(mo - mn); m.y = mn;
        mo = __shfl_xor(m.z, d); so = __shfl_xor(s.z, d);
        mn = fmaxf(m.z, mo); s.z = s.z * __expf(m.z - mn) + so * __expf(mo - mn); m.z = mn;
        mo = __shfl_xor(m.w, d); so = __shfl_xor(s.w, d);
        mn = fmaxf(m.w, mo); s.w = s.w * __expf(m.w - mn) + so * __expf(mo - mn); m.w = mn;
    }
    float4 inv;
    inv.x = 1.f / fmaxf(s.x, 1e-20f);
    inv.y = 1.f / fmaxf(s.y, 1e-20f);
    inv.z = 1.f / fmaxf(s.z, 1e-20f);
    inv.w = 1.f / fmaxf(s.w, 1e-20f);
    if (lane == 0) {
        *(float4*)(m_arr + (size_t)n * NHEAD) = m;
        *(float4*)(inv_arr + (size_t)n * NHEAD) = inv;
    }

    // ---- sweep 2: register-broadcast src + LDS-staged a + saddr gather ----
    float4 acc = make_float4(0.f, 0.f, 0.f, 0.f);
    const int laneoff = lane << 2;          // ushort index; 8B per lane
    for (int base = 0; base < deg; base += 64) {
        int i = base + lane;
        bool valid = i < deg;
        int sidx; float4 l;
        if (base == 0) { sidx = s0_save; l = l0_save; }
        else {
            int e = perm[o0 + (valid ? i : deg - 1)];
            sidx = src[e];
            float4 ev = *(const float4*)(el + (size_t)sidx * NHEAD);
            l.x = lrelu(ev.x + er4.x); l.y = lrelu(ev.y + er4.y);
            l.z = lrelu(ev.z + er4.z); l.w = lrelu(ev.w + er4.w);
        }
        float4 a;
        a.x = valid ? __expf(l.x - m.x) * inv.x : 0.f;
        a.y = valid ? __expf(l.y - m.y) * inv.y : 0.f;
        a.z = valid ? __expf(l.z - m.z) * inv.z : 0.f;
        a.w = valid ? __expf(l.w - m.w) * inv.w : 0.f;
        *(float4*)(aw + (lane << 2)) = a;   // wave-synchronous staging

        int nc = min(64, deg - base);
#pragma unroll 8
        for (int j = 0; j < nc; ++j) {
            int sj = __builtin_amdgcn_readlane(sidx, j);       // reg -> SGPR
            float av = aw[(j << 2) + h];                       // broadcast ds_read
            const unsigned short* rp = fsb + ((size_t)(unsigned)sj << 8) + laneoff;
            uint2 p = *(const uint2*)rp;                       // saddr + lane voff
            acc.x = fmaf(av, __uint_as_float(p.x << 16), acc.x);
            acc.y = fmaf(av, __uint_as_float(p.x & 0xffff0000u), acc.y);
            acc.z = fmaf(av, __uint_as_float(p.y << 16), acc.z);
            acc.w = fmaf(av, __uint_as_float(p.y & 0xffff0000u), acc.w);
        }
    }
    size_t ro = (size_t)n * 256 + (lane << 2);
    float4 r = *(float4*)(rst + ro);
    r.x += acc.x; r.y += acc.y; r.z += acc.z; r.w += acc.w;
    *(float4*)(rst + ro) = r;
}

// ---------------- a_out: edge-parallel, coalesced writes ----------------
__global__ __launch_bounds__(256) void aout_kernel(
    const int* __restrict__ src, const int* __restrict__ dst,
    const float* __restrict__ el, const float* __restrict__ er,
    const float* __restrict__ m_arr, const float* __restrict__ inv_arr,
    float* __restrict__ a_out)
{
    int e = blockIdx.x * 256 + threadIdx.x;
    if (e >= NEDGES) return;
    int sidx = src[e], d = dst[e];
    float4 ev = *(const float4*)(el + (size_t)sidx * NHEAD);
    float4 rv = *(const float4*)(er + (size_t)d * NHEAD);
    float4 m4 = *(const float4*)(m_arr + (size_t)d * NHEAD);
    float4 i4 = *(const float4*)(inv_arr + (size_t)d * NHEAD);
    float4 a;
    a.x = __expf(lrelu(ev.x + rv.x) - m4.x) * i4.x;
    a.y = __expf(lrelu(ev.y + rv.y) - m4.y) * i4.y;
    a.z = __expf(lrelu(ev.z + rv.z) - m4.z) * i4.z;
    a.w = __expf(lrelu(ev.w + rv.w) - m4.w) * i4.w;
    *(float4*)(a_out + (size_t)e * NHEAD) = a;
}

// ---------------- launch ----------------
extern "C" void kernel_launch(void* const* d_in, const int* in_sizes, int n_in,
                              void* d_out, int out_size, void* d_ws, size_t ws_size,
                              hipStream_t stream) {
    const float* feat   = (const float*)d_in[0];
    const int*   src    = (const int*)d_in[1];
    const int*   dst    = (const int*)d_in[2];
    const float* Wfc    = (const float*)d_in[3];
    const float* attn_l = (const float*)d_in[4];
    const float* attn_r = (const float*)d_in[5];
    const float* Wres   = (const float*)d_in[6];
    const float* bias   = (const float*)d_in[7];

    float* rst   = (float*)d_out;                              // N*256
    float* a_out = (float*)d_out + (size_t)NNODES * CDIM;      // E*4

    unsigned short* featb = (unsigned short*)d_ws;             // N*256 bf16
    unsigned short* fsb   = featb + (size_t)NNODES * CDIM;     // N*256 bf16
    unsigned short* Wb    = fsb + (size_t)NNODES * CDIM;       // 512*256 bf16
    float* el      = (float*)(Wb + 512 * 256);                 // N*4
    float* er      = el + (size_t)NNODES * NHEAD;              // N*4
    float* m_arr   = er + (size_t)NNODES * NHEAD;              // N*4
    float* inv_arr = m_arr + (size_t)NNODES * NHEAD;           // N*4
    int* cnt    = (int*)(inv_arr + (size_t)NNODES * NHEAD);    // N
    int* off    = cnt + NNODES;                                // N
    int* cursor = off + NNODES;                                // N
    int* total  = cursor + NNODES;                             // 4
    int* perm   = total + 4;                                   // E

    hipMemsetAsync(cnt, 0, NNODES * sizeof(int), stream);
    hipMemsetAsync(total, 0, 4 * sizeof(int), stream);

    cvt_feat<<<(NNODES * CDIM) / (256 * 4), 256, 0, stream>>>(feat, featb);
    cvt_w<<<(512 * 256) / (256 * 4), 256, 0, stream>>>(Wfc, Wres, Wb);

    // 782 row-blocks -> 98 groups of 8 -> grid 98*32 = 3136 (tail guarded)
    gemm_mfma<<<3136, 256, 0, stream>>>(featb, Wb, bias, attn_l, attn_r,
                                        fsb, rst, el, er);

    count_kernel<<<(NEDGES + 255) / 256, 256, 0, stream>>>(dst, cnt);
    offset_kernel<<<(NNODES + 255) / 256, 256, 0, stream>>>(cnt, off, cursor, total);
    scatter_kernel<<<(NEDGES + 255) / 256, 256, 0, stream>>>(dst, cursor, perm);

    agg_kernel<<<NNODES / 4, 256, 0, stream>>>(src, perm, off, cnt, el, er,
                                               fsb, rst, m_arr, inv_arr);
    aout_kernel<<<(NEDGES + 255) / 256, 256, 0, stream>>>(src, dst, el, er,
                                                          m_arr, inv_arr, a_out);
}